// Round 9
// baseline (268.097 us; speedup 1.0000x reference)
//
#include <hip/hip_runtime.h>
#include <hip/hip_bf16.h>

#define N_NODES 50000
#define IN_CH 64
#define HC 128          // HEADS * OUT_CH
#define CAP 48          // per-node bucket capacity (incl. self-loop slot 0); P(deg>47)~0
#define NEG_SLOPE 0.2f
#define BN_EPS 1e-5f

// ---- ws layout (bytes) ----
// 0        : int   flag_int64
// 64       : float mean_sums[3]
// 1024     : float bn_sums[256]   (sum[128], sumsq[128])
// 0x10000  : int   deg16[N_NODES*16]      (3.2 MB; one counter per 64B line, slot0=self)
// 0x350000 : int   srcs[N_NODES*CAP]      (9.6 MB)
// 14<<20   : float4 pos4[N_NODES]         (800 KB)
// 1<<24    : uint  xl_bf[N_NODES*64]      (12.8 MB, bf16x2 per word)

// DPP butterfly adds (pure VALU — no lgkm, unlike __shfl_xor's ds_bpermute)
__device__ __forceinline__ float quad_xor1_add(float v) {
  int t = __builtin_amdgcn_update_dpp(0, __float_as_int(v), 0xB1, 0xF, 0xF, true); // quad_perm [1,0,3,2]
  return v + __int_as_float(t);
}
__device__ __forceinline__ float quad_xor2_add(float v) {
  int t = __builtin_amdgcn_update_dpp(0, __float_as_int(v), 0x4E, 0xF, 0xF, true); // quad_perm [2,3,0,1]
  return v + __int_as_float(t);
}
__device__ __forceinline__ float half_mirror_add(float v) {
  int t = __builtin_amdgcn_update_dpp(0, __float_as_int(v), 0x141, 0xF, 0xF, true); // row_half_mirror (l^7 within 8)
  return v + __int_as_float(t);
}

// ---------------------------------------------------------------- gemm + fused init
__global__ __launch_bounds__(256) void k_gemm(const float* __restrict__ x,
                                              const float* __restrict__ Wl,
                                              const float* __restrict__ Wr,
                                              unsigned int* __restrict__ xl_bf,
                                              float* __restrict__ xr_out,
                                              int* __restrict__ deg16,
                                              float* __restrict__ mean_sums,
                                              float* __restrict__ bn_sums,
                                              int* __restrict__ flag,
                                              const int* __restrict__ eidx,
                                              const float* __restrict__ pos,
                                              float4* __restrict__ pos4) {
  // ---- fused init ----
  {
    int gtid = blockIdx.x * 256 + threadIdx.x;
    if (gtid < N_NODES) {
      deg16[gtid << 4] = 1;
      pos4[gtid] = make_float4(pos[3 * gtid], pos[3 * gtid + 1], pos[3 * gtid + 2], 0.f);
    }
    if (gtid < 256) bn_sums[gtid] = 0.f;
    if (gtid < 3) mean_sums[gtid] = 0.f;
    if (blockIdx.x == 0 && threadIdx.x < 64) {
      int w = eidx[2 * threadIdx.x + 1];
      unsigned long long nz = __ballot(w != 0);
      if (threadIdx.x == 0) flag[0] = (nz == 0ULL) ? 1 : 0;
    }
  }

  __shared__ float xsT[IN_CH][20];                // transposed x tile, padded
  __shared__ __hip_bfloat162 wsm[IN_CH][128];     // 32 KB
  const int t = threadIdx.x;
  const int row0 = blockIdx.x * 16;

  for (int i = 0; i < 32; ++i) {
    int k = i * 2 + (t >> 7);
    int p = t & 127;
    int cc = p * 2;
    float2 wv;
    if (cc < 128) wv = *(const float2*)(Wl + k * 128 + cc);
    else          wv = *(const float2*)(Wr + k * 128 + (cc - 128));
    wsm[k][p] = __float22bfloat162_rn(wv);
  }
  {
    int r = t >> 4, c4 = (t & 15) * 4;
    float4 v = *(const float4*)(x + (row0 + r) * IN_CH + c4);
    xsT[c4][r] = v.x; xsT[c4 + 1][r] = v.y; xsT[c4 + 2][r] = v.z; xsT[c4 + 3][r] = v.w;
  }
  __syncthreads();

  const int ct = t & 63;
  const int rt = t >> 6;
  const int c4 = ct * 4;
  const int r4 = rt * 4;

  float acc[4][4];
  #pragma unroll
  for (int a = 0; a < 4; ++a)
    #pragma unroll
    for (int b = 0; b < 4; ++b) acc[a][b] = 0.f;

  #pragma unroll 8
  for (int k = 0; k < IN_CH; ++k) {
    uint2 wraw = *(const uint2*)&wsm[k][ct * 2];
    float2 f01 = __bfloat1622float2(*(__hip_bfloat162*)&wraw.x);
    float2 f23 = __bfloat1622float2(*(__hip_bfloat162*)&wraw.y);
    float wv[4] = {f01.x, f01.y, f23.x, f23.y};
    float4 xv4 = *(const float4*)&xsT[k][r4];
    float xv[4] = {xv4.x, xv4.y, xv4.z, xv4.w};
    #pragma unroll
    for (int a = 0; a < 4; ++a)
      #pragma unroll
      for (int b = 0; b < 4; ++b) acc[a][b] = fmaf(xv[a], wv[b], acc[a][b]);
  }

  #pragma unroll
  for (int a = 0; a < 4; ++a) {
    int row = row0 + r4 + a;
    if (c4 < 128) {
      __hip_bfloat162 b01 = __float22bfloat162_rn(make_float2(acc[a][0], acc[a][1]));
      __hip_bfloat162 b23 = __float22bfloat162_rn(make_float2(acc[a][2], acc[a][3]));
      uint2 u;
      u.x = *(unsigned int*)&b01;
      u.y = *(unsigned int*)&b23;
      *(uint2*)(xl_bf + row * 64 + (c4 >> 1)) = u;
    } else {
      float4 v = make_float4(acc[a][0], acc[a][1], acc[a][2], acc[a][3]);
      *(float4*)(xr_out + row * HC + (c4 - 128)) = v;
    }
  }
}

// ---------------------------------------------------------------- edge pass: 8 edges/thread; deg padded to 1 counter/line
__global__ __launch_bounds__(256) void k_edges(const int* __restrict__ eidx,
                                               const float4* __restrict__ pos4,
                                               int* __restrict__ deg16,
                                               int* __restrict__ srcs,
                                               float* __restrict__ mean_sums,
                                               const int* __restrict__ flag,
                                               int E) {
  const bool w64 = flag[0] != 0;
  const int tid = blockIdx.x * 256 + threadIdx.x;
  const int base = tid * 8;
  float sx = 0.f, sy = 0.f, sz = 0.f;

  const bool vec_ok = w64 ? ((E & 1) == 0) : ((E & 3) == 0);

  if (base + 8 <= E && vec_ok) {
    int s[8], d[8];
    if (w64) {
      const int4* ps = (const int4*)(eidx + 2 * base);
      int4 A = ps[0], B = ps[1], C = ps[2], D = ps[3];
      s[0]=A.x; s[1]=A.z; s[2]=B.x; s[3]=B.z; s[4]=C.x; s[5]=C.z; s[6]=D.x; s[7]=D.z;
      const int4* pd = (const int4*)(eidx + 2 * E + 2 * base);
      A = pd[0]; B = pd[1]; C = pd[2]; D = pd[3];
      d[0]=A.x; d[1]=A.z; d[2]=B.x; d[3]=B.z; d[4]=C.x; d[5]=C.z; d[6]=D.x; d[7]=D.z;
    } else {
      int4 A = *(const int4*)(eidx + base);
      int4 B = *(const int4*)(eidx + base + 4);
      s[0]=A.x; s[1]=A.y; s[2]=A.z; s[3]=A.w; s[4]=B.x; s[5]=B.y; s[6]=B.z; s[7]=B.w;
      A = *(const int4*)(eidx + E + base);
      B = *(const int4*)(eidx + E + base + 4);
      d[0]=A.x; d[1]=A.y; d[2]=A.z; d[3]=A.w; d[4]=B.x; d[5]=B.y; d[6]=B.z; d[7]=B.w;
    }
    int slot[8];
    #pragma unroll
    for (int k = 0; k < 8; ++k) slot[k] = atomicAdd(&deg16[d[k] << 4], 1);
    #pragma unroll
    for (int k = 0; k < 8; ++k)
      if (slot[k] < CAP) srcs[d[k] * CAP + slot[k]] = s[k];
    #pragma unroll
    for (int k = 0; k < 8; ++k) {
      float4 ps = pos4[s[k]], pd = pos4[d[k]];
      sx += ps.x - pd.x; sy += ps.y - pd.y; sz += ps.z - pd.z;
    }
  } else if (base < E) {
    int hi = min(base + 8, E);
    for (int e = base; e < hi; ++e) {
      int s, d;
      if (w64) { s = eidx[2 * e]; d = eidx[2 * (E + e)]; }
      else     { s = eidx[e];     d = eidx[E + e]; }
      int o = atomicAdd(&deg16[d << 4], 1);
      if (o < CAP) srcs[d * CAP + o] = s;
      float4 ps = pos4[s], pd = pos4[d];
      sx += ps.x - pd.x; sy += ps.y - pd.y; sz += ps.z - pd.z;
    }
  }

  #pragma unroll
  for (int m = 1; m < 64; m <<= 1) {
    sx += __shfl_xor(sx, m); sy += __shfl_xor(sy, m); sz += __shfl_xor(sz, m);
  }
  __shared__ float red[4][3];
  int wave = threadIdx.x >> 6, lane = threadIdx.x & 63;
  if (lane == 0) { red[wave][0] = sx; red[wave][1] = sy; red[wave][2] = sz; }
  __syncthreads();
  if (threadIdx.x == 0) {
    float a = 0.f, b = 0.f, c = 0.f;
    for (int w = 0; w < 4; ++w) { a += red[w][0]; b += red[w][1]; c += red[w][2]; }
    unsafeAtomicAdd(&mean_sums[0], a);
    unsafeAtomicAdd(&mean_sums[1], b);
    unsafeAtomicAdd(&mean_sums[2], c);
  }
}

// ---------------------------------------------------------------- half-wave k_agg: 32 lanes/edge, 4 ch/lane,
// 2 groups/iter = 4 independent VMEM chains; DPP-only score reduce; fused BN stats.
__global__ __launch_bounds__(256) void k_agg(const unsigned int* __restrict__ xl_bf,
                                             float* __restrict__ xr_out,   // in: xr, out: pre-BN out
                                             const float4* __restrict__ pos4,
                                             const float* __restrict__ att,
                                             const float* __restrict__ We,
                                             const float* __restrict__ mean_sums,
                                             const int* __restrict__ srcs,
                                             const int* __restrict__ deg16,
                                             float* __restrict__ bn_sums,
                                             float invE) {
  __shared__ float bnloc[256];     // [sum 0..127 | sumsq 128..255]
  bnloc[threadIdx.x] = 0.f;
  __syncthreads();

  const int lane = threadIdx.x & 63;
  const int half = lane >> 5;
  const int l5 = lane & 31;
  const int c = l5 << 2;            // 4 channels per lane; head = l5>>3 (8 lanes/head)

  const float4 at4 = *(const float4*)(att + c);
  const float4 w0 = *(const float4*)(We + c);
  const float4 w1 = *(const float4*)(We + 128 + c);
  const float4 w2 = *(const float4*)(We + 256 + c);
  const float m0 = mean_sums[0] * invE;
  const float m1 = mean_sums[1] * invE;
  const float m2 = mean_sums[2] * invE;

  const int gw = blockIdx.x * 4 + (threadIdx.x >> 6);
  const int W = gridDim.x * 4;

  for (int i = gw; i < N_NODES; i += W) {
    const float4 xr4 = *(const float4*)(xr_out + i * HC + c);
    const float4 myp = pos4[i];
    const float px = myp.x, py = myp.y, pz = myp.z;
    const int di = min(deg16[i << 4], CAP);
    const int sreg = srcs[i * CAP + min(lane, CAP - 1)];  // bucket row staged in registers
    float a0 = 0.f, a1 = 0.f, a2 = 0.f, a3 = 0.f, den = 0.f;

    auto compute = [&](uint2 raw, float4 pp, bool valid) {
      float dx = pp.x - px, dy = pp.y - py, dz = pp.z - pz;
      float2 x01 = __bfloat1622float2(*(__hip_bfloat162*)&raw.x);
      float2 x23 = __bfloat1622float2(*(__hip_bfloat162*)&raw.y);
      float t0 = x01.x + xr4.x; t0 = fmaf(dx, w0.x, t0); t0 = fmaf(dy, w1.x, t0); t0 = fmaf(dz, w2.x, t0);
      float t1 = x01.y + xr4.y; t1 = fmaf(dx, w0.y, t1); t1 = fmaf(dy, w1.y, t1); t1 = fmaf(dz, w2.y, t1);
      float t2 = x23.x + xr4.z; t2 = fmaf(dx, w0.z, t2); t2 = fmaf(dy, w1.z, t2); t2 = fmaf(dz, w2.z, t2);
      float t3 = x23.y + xr4.w; t3 = fmaf(dx, w0.w, t3); t3 = fmaf(dy, w1.w, t3); t3 = fmaf(dz, w2.w, t3);
      float l0 = fmaf(NEG_SLOPE, fminf(t0, 0.f), fmaxf(t0, 0.f));
      float l1 = fmaf(NEG_SLOPE, fminf(t1, 0.f), fmaxf(t1, 0.f));
      float l2 = fmaf(NEG_SLOPE, fminf(t2, 0.f), fmaxf(t2, 0.f));
      float l3 = fmaf(NEG_SLOPE, fminf(t3, 0.f), fmaxf(t3, 0.f));
      float sc = l0 * at4.x;
      sc = fmaf(l1, at4.y, sc); sc = fmaf(l2, at4.z, sc); sc = fmaf(l3, at4.w, sc);
      sc = quad_xor1_add(sc);
      sc = quad_xor2_add(sc);
      sc = half_mirror_add(sc);          // 8-lane head group reduced, VALU-only
      float p = valid ? __expf(sc) : 0.f;
      den += p;
      a0 = fmaf(p, x01.x, a0); a1 = fmaf(p, x01.y, a1);
      a2 = fmaf(p, x23.x, a2); a3 = fmaf(p, x23.y, a3);
    };

    // peeled first iteration: group A = slots {0,1} (slot 0 = self-loop), group B = slots {2,3}
    {
      int jA = half;
      int sA = __shfl(sreg, jA);
      bool vA = jA < di;                 // half0 always valid
      if (half == 0 || !vA) sA = i;
      int jB = 2 + half;
      int sB = __shfl(sreg, jB);
      bool vB = jB < di;
      if (!vB) sB = i;
      uint2 rawA = *(const uint2*)(xl_bf + (sA << 6) + (l5 << 1));
      float4 ppA = pos4[sA];
      uint2 rawB = *(const uint2*)(xl_bf + (sB << 6) + (l5 << 1));
      float4 ppB = pos4[sB];
      if (half == 0) ppA = make_float4(px + m0, py + m1, pz + m2, 0.f);
      compute(rawA, ppA, vA);
      compute(rawB, ppB, vB);
    }

    for (int j = 4; j < di; j += 4) {
      int jA = j + half;
      int jB = j + 2 + half;
      int sA = __shfl(sreg, jA);
      int sB = __shfl(sreg, jB);
      bool vA = jA < di;
      bool vB = jB < di;
      if (!vA) sA = i;
      if (!vB) sB = i;
      uint2 rawA = *(const uint2*)(xl_bf + (sA << 6) + (l5 << 1));
      float4 ppA = pos4[sA];
      uint2 rawB = *(const uint2*)(xl_bf + (sB << 6) + (l5 << 1));
      float4 ppB = pos4[sB];
      compute(rawA, ppA, vA);
      compute(rawB, ppB, vB);
    }

    // combine the two half-wave partials
    den += __shfl_xor(den, 32);
    a0 += __shfl_xor(a0, 32);
    a1 += __shfl_xor(a1, 32);
    a2 += __shfl_xor(a2, 32);
    a3 += __shfl_xor(a3, 32);

    float inv = 1.f / (den + 1e-16f);
    if (half == 0) {
      float o0 = a0 * inv, o1 = a1 * inv, o2 = a2 * inv, o3 = a3 * inv;
      *(float4*)(xr_out + i * HC + c) = make_float4(o0, o1, o2, o3);
      atomicAdd(&bnloc[c],     o0); atomicAdd(&bnloc[128 + c],     o0 * o0);
      atomicAdd(&bnloc[c + 1], o1); atomicAdd(&bnloc[128 + c + 1], o1 * o1);
      atomicAdd(&bnloc[c + 2], o2); atomicAdd(&bnloc[128 + c + 2], o2 * o2);
      atomicAdd(&bnloc[c + 3], o3); atomicAdd(&bnloc[128 + c + 3], o3 * o3);
    }
  }

  __syncthreads();
  unsafeAtomicAdd(&bn_sums[threadIdx.x], bnloc[threadIdx.x]);
}

// ---------------------------------------------------------------- BN apply (in place)
__global__ __launch_bounds__(256) void k_bnapply(float* __restrict__ out,
                                                 const float* __restrict__ bn_sums,
                                                 const float* __restrict__ gamma,
                                                 const float* __restrict__ beta,
                                                 int n4) {
  const int stride = gridDim.x * blockDim.x;
  const float invN = 1.f / (float)N_NODES;
  for (int i = blockIdx.x * blockDim.x + threadIdx.x; i < n4; i += stride) {
    int c = (i & 31) * 4;
    float4 v = ((float4*)out)[i];
    float4 s = *(const float4*)(bn_sums + c);
    float4 q = *(const float4*)(bn_sums + 128 + c);
    float4 g = *(const float4*)(gamma + c);
    float4 b = *(const float4*)(beta + c);
    float mu, var, rstd;
    mu = s.x * invN; var = q.x * invN - mu * mu; rstd = rsqrtf(var + BN_EPS);
    v.x = (v.x - mu) * rstd * g.x + b.x;
    mu = s.y * invN; var = q.y * invN - mu * mu; rstd = rsqrtf(var + BN_EPS);
    v.y = (v.y - mu) * rstd * g.y + b.y;
    mu = s.z * invN; var = q.z * invN - mu * mu; rstd = rsqrtf(var + BN_EPS);
    v.z = (v.z - mu) * rstd * g.z + b.z;
    mu = s.w * invN; var = q.w * invN - mu * mu; rstd = rsqrtf(var + BN_EPS);
    v.w = (v.w - mu) * rstd * g.w + b.w;
    ((float4*)out)[i] = v;
  }
}

extern "C" void kernel_launch(void* const* d_in, const int* in_sizes, int n_in,
                              void* d_out, int out_size, void* d_ws, size_t ws_size,
                              hipStream_t stream) {
  const float* x     = (const float*)d_in[0];
  const float* pos   = (const float*)d_in[1];
  const int*   eidx  = (const int*)d_in[2];
  const float* Wl    = (const float*)d_in[3];
  const float* Wr    = (const float*)d_in[4];
  const float* We    = (const float*)d_in[5];
  const float* att   = (const float*)d_in[6];
  const float* gamma = (const float*)d_in[7];
  const float* beta  = (const float*)d_in[8];
  float* out = (float*)d_out;
  const int E = in_sizes[2] / 2;

  char* ws = (char*)d_ws;
  int*   flag      = (int*)(ws + 0);
  float* mean_sums = (float*)(ws + 64);
  float* bn_sums   = (float*)(ws + 1024);
  int*   deg16     = (int*)(ws + 0x10000);
  int*   srcs      = (int*)(ws + 0x350000);
  float4* pos4     = (float4*)(ws + (14 << 20));
  unsigned int* xl_bf = (unsigned int*)(ws + (1 << 24));

  k_gemm<<<N_NODES / 16, 256, 0, stream>>>(x, Wl, Wr, xl_bf, out,
                                           deg16, mean_sums, bn_sums, flag, eidx, pos, pos4);
  int eblocks = (E + 2047) / 2048;   // 8 edges per thread
  k_edges<<<eblocks, 256, 0, stream>>>(eidx, pos4, deg16, srcs, mean_sums, flag, E);
  k_agg<<<2048, 256, 0, stream>>>(xl_bf, out, pos4, att, We, mean_sums, srcs, deg16,
                                  bn_sums, 1.f / (float)E);
  k_bnapply<<<512, 256, 0, stream>>>(out, bn_sums, gamma, beta, out_size / 4);
}